// Round 1
// baseline (11872.839 us; speedup 1.0000x reference)
//
#include <hip/hip_runtime.h>
#include <hip/hip_bf16.h>
#include <cstdint>
#include <cstddef>

#define NN 20000
#define HH 128
#define MM 16
#define KK 4000
#define EE 400000

__device__ __forceinline__ float gelu_f(float x) {
  // jax.nn.gelu(approximate=False) = x * 0.5 * (1 + erf(x/sqrt(2)))
  return 0.5f * x * (1.0f + erff(x * 0.70710678118654752440f));
}

// ---------------- GCN helper kernels ----------------

__global__ void zero2_kernel(int* __restrict__ a, int* __restrict__ b, int n) {
  int i = blockIdx.x * 256 + threadIdx.x;
  if (i < n) { a[i] = 0; b[i] = 0; }
}

__global__ void count_kernel(const int* __restrict__ dst, int* __restrict__ cnt, int n) {
  int e = blockIdx.x * 256 + threadIdx.x;
  if (e < n) atomicAdd(&cnt[dst[e]], 1);
}

__global__ void dinv_kernel(const int* __restrict__ cnt, float* __restrict__ dinv, int n) {
  int i = blockIdx.x * 256 + threadIdx.x;
  if (i < n) dinv[i] = rsqrtf((float)(cnt[i] + 1));  // +1 self-loop, always >= 1
}

__global__ void scan_kernel(const int* __restrict__ cnt, int* __restrict__ offs, int n) {
  __shared__ int sh[1024];
  __shared__ int carry_s;
  int tid = threadIdx.x;
  if (tid == 0) carry_s = 0;
  __syncthreads();
  for (int base = 0; base < n; base += 1024) {
    int i = base + tid;
    int v = (i < n) ? cnt[i] : 0;
    sh[tid] = v;
    __syncthreads();
    for (int off = 1; off < 1024; off <<= 1) {
      int t = (tid >= off) ? sh[tid - off] : 0;
      __syncthreads();
      sh[tid] += t;
      __syncthreads();
    }
    int carry = carry_s;
    if (i < n) offs[i] = carry + sh[tid] - v;  // exclusive
    __syncthreads();
    if (tid == 1023) carry_s = carry + sh[1023];
    __syncthreads();
  }
  if (tid == 0) offs[n] = carry_s;
}

__global__ void fillcsr_kernel(const int* __restrict__ esrc, const int* __restrict__ edst,
                               const int* __restrict__ offs, int* __restrict__ cursor,
                               const float* __restrict__ dinv,
                               int* __restrict__ csrc, float* __restrict__ cnorm, int n) {
  int e = blockIdx.x * 256 + threadIdx.x;
  if (e < n) {
    int s = esrc[e], d = edst[e];
    int pos = offs[d] + atomicAdd(&cursor[d], 1);
    csrc[pos] = s;
    cnorm[pos] = dinv[s] * dinv[d];
  }
}

// Y[i,c] = sum_{j in in-edges(i)} X[src_j,c]*norm_j + X[i,c]*dinv[i]^2 + bias[c]  (opt relu)
__global__ __launch_bounds__(128) void agg_kernel(const float* __restrict__ X,
    const int* __restrict__ csrc, const float* __restrict__ cnorm,
    const int* __restrict__ offs, const float* __restrict__ dinv,
    const float* __restrict__ bias, int relu, float* __restrict__ Y) {
  int i = blockIdx.x, c = threadIdx.x;
  float di = dinv[i];
  float acc = X[(size_t)i * HH + c] * di * di;
  int s = offs[i], e = offs[i + 1];
  for (int j = s; j < e; ++j) {
    acc += X[(size_t)csrc[j] * HH + c] * cnorm[j];
  }
  acc += bias[c];
  if (relu) acc = fmaxf(acc, 0.f);
  Y[(size_t)i * HH + c] = acc;
}

// Y[r,o] = sum_k X[r,k] * W[o,k]   (W row-major [out,in], no bias)
__global__ __launch_bounds__(128) void gemm128_kernel(const float* __restrict__ X,
    const float* __restrict__ W, float* __restrict__ Y, int nrows) {
  __shared__ float Ws[128 * 129];
  __shared__ float Xs[8 * 128];
  int tid = threadIdx.x;
  for (int idx = tid; idx < 16384; idx += 128) {
    int o = idx >> 7, k = idx & 127;
    Ws[o * 129 + k] = W[idx];
  }
  __syncthreads();
  for (int row0 = blockIdx.x * 8; row0 < nrows; row0 += gridDim.x * 8) {
    int nr = min(8, nrows - row0);
    for (int idx = tid; idx < nr * 128; idx += 128) Xs[idx] = X[(size_t)row0 * 128 + idx];
    __syncthreads();
    float acc[8] = {0, 0, 0, 0, 0, 0, 0, 0};
    for (int k = 0; k < 128; ++k) {
      float w = Ws[tid * 129 + k];
#pragma unroll
      for (int r = 0; r < 8; ++r) acc[r] += w * Xs[r * 128 + k];
    }
    for (int r = 0; r < nr; ++r) Y[(size_t)(row0 + r) * 128 + tid] = acc[r];
    __syncthreads();
  }
}

__global__ void mask_kernel(const int* __restrict__ nodes, float* __restrict__ H, int kn) {
  int idx = blockIdx.x * 256 + threadIdx.x;
  if (idx < kn * HH) {
    int j = idx >> 7, c = idx & 127;
    H[(size_t)nodes[j] * HH + c] = 0.f;
  }
}

__global__ void bcast_kernel(float* __restrict__ out, int total) {
  int idx = blockIdx.x * 256 + threadIdx.x + 128;
  if (idx < total) out[idx] = out[idx & 127];
}

// ---------------- fused MLP-mixer + mean kernel ----------------
// One node per block iteration; 256 threads; grid-stride over nodes.
// LDS: ch_w1/ch_w2 f32 staged with XOR-swizzled float4 layout (conflict-free
// per-lane row reads), x/z tiles [16][132].

__device__ __forceinline__ int wswz(int o, int k) {
  // dword index for element (o,k) of a 128x128 matrix, row pitch 132 dwords.
  return o * 132 + (((k >> 2) ^ ((o >> 3) & 7)) << 2) + (k & 3);
}

__global__ __launch_bounds__(256, 1) void mixer_kernel(
    const float* __restrict__ hbufs,  // [7][NN][HH]
    int nfill,                        // = t (number of filled tokens)
    const float* __restrict__ tn_g, const float* __restrict__ tn_b,
    const float* __restrict__ tok_w1, const float* __restrict__ tok_b1,
    const float* __restrict__ tok_w2, const float* __restrict__ tok_b2,
    const float* __restrict__ cn_g, const float* __restrict__ cn_b,
    const float* __restrict__ ch_w1, const float* __restrict__ ch_b1,
    const float* __restrict__ ch_w2, const float* __restrict__ ch_b2,
    float* __restrict__ out,          // out + t*NN*HH
    int node0, int nodeN) {
  __shared__ float W1s[128 * 132];
  __shared__ float W2s[128 * 132];
  __shared__ float xs[16 * 132];
  __shared__ float zs[16 * 132];
  __shared__ float tw1[256], tw2[256], tb1[16], tb2[16];
  __shared__ float tg[128], tb[128], cg[128], cb[128], cb1[128], cb2[128];

  const int tid = threadIdx.x;
  for (int idx = tid; idx < 16384; idx += 256) {
    int o = idx >> 7, k = idx & 127;
    int sw = wswz(o, k);
    W1s[sw] = ch_w1[idx];
    W2s[sw] = ch_w2[idx];
  }
  tw1[tid] = tok_w1[tid & 255];
  tw2[tid] = tok_w2[tid & 255];
  if (tid < 16) { tb1[tid] = tok_b1[tid]; tb2[tid] = tok_b2[tid]; }
  if (tid < 128) {
    tg[tid] = tn_g[tid]; tb[tid] = tn_b[tid];
    cg[tid] = cn_g[tid]; cb[tid] = cn_b[tid];
    cb1[tid] = ch_b1[tid]; cb2[tid] = ch_b2[tid];
  }
  __syncthreads();

  const int oc = tid & 127;      // output channel for channel-MLP
  const int hf = tid >> 7;       // which 8-token half
  const int r0 = hf * 8;
  const int lr = tid >> 4;       // LN: row 0..15
  const int ls = tid & 15;       // LN: sub-slot 0..15 (8 channels each)

  for (int node = node0 + blockIdx.x; node < nodeN; node += gridDim.x) {
    // ---- load window tokens (zeros for unfilled rows) ----
#pragma unroll
    for (int u = 0; u < 8; ++u) {
      int idx = u * 256 + tid;
      int r = idx >> 7, c = idx & 127;
      int src_t = r - (MM - nfill);
      float v = 0.f;
      if (src_t >= 0) v = hbufs[(size_t)src_t * NN * HH + (size_t)node * HH + c];
      xs[r * 132 + c] = v;
    }
    __syncthreads();

    // ---- LN1 (token norm) -> zs ----
    {
      float s = 0.f, ss = 0.f;
      int base = lr * 132 + ls * 8;
      float vals[8];
#pragma unroll
      for (int u = 0; u < 8; ++u) { float v = xs[base + u]; vals[u] = v; s += v; ss += v * v; }
#pragma unroll
      for (int d = 1; d < 16; d <<= 1) { s += __shfl_xor(s, d); ss += __shfl_xor(ss, d); }
      float mu = s * (1.f / 128.f);
      float var = fmaxf(ss * (1.f / 128.f) - mu * mu, 0.f);
      float rs = rsqrtf(var + 1e-5f);
#pragma unroll
      for (int u = 0; u < 8; ++u) {
        int c = ls * 8 + u;
        zs[lr * 132 + c] = (vals[u] - mu) * rs * tg[c] + tb[c];
      }
    }
    __syncthreads();

    // ---- token-mixing MLP (per channel), x += tok2(gelu(tok1(y))) ----
    if (tid < 128) {
      float v[16];
#pragma unroll
      for (int r = 0; r < 16; ++r) v[r] = zs[r * 132 + tid];
      float g[16];
#pragma unroll
      for (int hd = 0; hd < 16; ++hd) {
        float a = tb1[hd];
#pragma unroll
        for (int r = 0; r < 16; ++r) a += tw1[hd * 16 + r] * v[r];
        g[hd] = gelu_f(a);
      }
#pragma unroll
      for (int r = 0; r < 16; ++r) {
        float a = tb2[r];
#pragma unroll
        for (int hd = 0; hd < 16; ++hd) a += tw2[r * 16 + hd] * g[hd];
        xs[r * 132 + tid] += a;
      }
    }
    __syncthreads();

    // ---- LN2 (channel norm) -> zs ----
    {
      float s = 0.f, ss = 0.f;
      int base = lr * 132 + ls * 8;
      float vals[8];
#pragma unroll
      for (int u = 0; u < 8; ++u) { float v = xs[base + u]; vals[u] = v; s += v; ss += v * v; }
#pragma unroll
      for (int d = 1; d < 16; d <<= 1) { s += __shfl_xor(s, d); ss += __shfl_xor(ss, d); }
      float mu = s * (1.f / 128.f);
      float var = fmaxf(ss * (1.f / 128.f) - mu * mu, 0.f);
      float rs = rsqrtf(var + 1e-5f);
#pragma unroll
      for (int u = 0; u < 8; ++u) {
        int c = ls * 8 + u;
        zs[lr * 132 + c] = (vals[u] - mu) * rs * cg[c] + cb[c];
      }
    }
    __syncthreads();

    // ---- channel MLP matmul 1: hidden = gelu(z @ W1^T + b1) ----
    float gg[8];
    {
      float acc[8];
#pragma unroll
      for (int r = 0; r < 8; ++r) acc[r] = cb1[oc];
      for (int k = 0; k < 128; k += 4) {
        int sw = oc * 132 + (((k >> 2) ^ ((oc >> 3) & 7)) << 2);
        float4 w4 = *(const float4*)&W1s[sw];
#pragma unroll
        for (int r = 0; r < 8; ++r) {
          float4 z4 = *(const float4*)&zs[(r0 + r) * 132 + k];
          acc[r] += w4.x * z4.x + w4.y * z4.y + w4.z * z4.z + w4.w * z4.w;
        }
      }
#pragma unroll
      for (int r = 0; r < 8; ++r) gg[r] = gelu_f(acc[r]);
    }
    __syncthreads();
#pragma unroll
    for (int r = 0; r < 8; ++r) zs[(r0 + r) * 132 + oc] = gg[r];
    __syncthreads();

    // ---- channel MLP matmul 2 + residual + partial token-mean ----
    {
      float acc[8];
#pragma unroll
      for (int r = 0; r < 8; ++r) acc[r] = cb2[oc];
      for (int k = 0; k < 128; k += 4) {
        int sw = oc * 132 + (((k >> 2) ^ ((oc >> 3) & 7)) << 2);
        float4 w4 = *(const float4*)&W2s[sw];
#pragma unroll
        for (int r = 0; r < 8; ++r) {
          float4 z4 = *(const float4*)&zs[(r0 + r) * 132 + k];
          acc[r] += w4.x * z4.x + w4.y * z4.y + w4.z * z4.z + w4.w * z4.w;
        }
      }
      float ps = 0.f;
#pragma unroll
      for (int r = 0; r < 8; ++r) ps += xs[(r0 + r) * 132 + oc] + acc[r];
      __syncthreads();                 // residual reads done before overwrite
      xs[hf * 132 + oc] = ps;
    }
    __syncthreads();
    if (tid < 128) out[(size_t)node * HH + tid] = (xs[tid] + xs[132 + tid]) * (1.f / 16.f);
    __syncthreads();                   // protect xs before next node's load
  }
}

// ---------------- launch ----------------

extern "C" void kernel_launch(void* const* d_in, const int* in_sizes, int n_in,
                              void* d_out, int out_size, void* d_ws, size_t ws_size,
                              hipStream_t stream) {
  const int* node_t   = (const int*)d_in[0];
  const int* edges    = (const int*)d_in[1];
  const float* emb    = (const float*)d_in[3];
  const float* convW1 = (const float*)d_in[4];
  const float* convb1 = (const float*)d_in[5];
  const float* convW2 = (const float*)d_in[6];
  const float* convb2 = (const float*)d_in[7];
  const float* tn_g   = (const float*)d_in[8];
  const float* tn_b   = (const float*)d_in[9];
  const float* tok_w1 = (const float*)d_in[10];
  const float* tok_b1 = (const float*)d_in[11];
  const float* tok_w2 = (const float*)d_in[12];
  const float* tok_b2 = (const float*)d_in[13];
  const float* cn_g   = (const float*)d_in[14];
  const float* cn_b   = (const float*)d_in[15];
  const float* ch_w1  = (const float*)d_in[16];
  const float* ch_b1  = (const float*)d_in[17];
  const float* ch_w2  = (const float*)d_in[18];
  const float* ch_b2  = (const float*)d_in[19];
  float* out = (float*)d_out;

  char* ws = (char*)d_ws;
  size_t off = 0;
  auto alloc = [&](size_t bytes) -> void* {
    void* p = ws + off;
    off += (bytes + 511) & ~(size_t)511;
    return p;
  };
  float* xw1   = (float*)alloc((size_t)NN * HH * 4);
  float* hbufs = (float*)alloc((size_t)7 * NN * HH * 4);
  float* h     = (float*)alloc((size_t)NN * HH * 4);
  float* h2    = (float*)alloc((size_t)NN * HH * 4);
  float* dinv  = (float*)alloc((size_t)NN * 4);
  int*   cnt   = (int*)alloc((size_t)NN * 4);
  int*   cursor= (int*)alloc((size_t)NN * 4);
  int*   offs  = (int*)alloc((size_t)(NN + 1) * 4);
  int*   csrc  = (int*)alloc((size_t)EE * 4);
  float* cnorm = (float*)alloc((size_t)EE * 4);

  // xw1 = emb @ convW1^T  (constant across steps)
  gemm128_kernel<<<512, 128, 0, stream>>>(emb, convW1, xw1, NN);

  // GCN per step t=0..6 (hbuf[7] is never consumed by any output)
  for (int t = 0; t < 7; ++t) {
    const int* es = edges + (size_t)t * 2 * EE;
    const int* ed = es + EE;
    zero2_kernel<<<(NN + 255) / 256, 256, 0, stream>>>(cnt, cursor, NN);
    count_kernel<<<(EE + 255) / 256, 256, 0, stream>>>(ed, cnt, EE);
    dinv_kernel<<<(NN + 255) / 256, 256, 0, stream>>>(cnt, dinv, NN);
    scan_kernel<<<1, 1024, 0, stream>>>(cnt, offs, NN);
    fillcsr_kernel<<<(EE + 255) / 256, 256, 0, stream>>>(es, ed, offs, cursor, dinv,
                                                         csrc, cnorm, EE);
    agg_kernel<<<NN, 128, 0, stream>>>(xw1, csrc, cnorm, offs, dinv, convb1, 1, h);
    gemm128_kernel<<<512, 128, 0, stream>>>(h, convW2, h2, NN);
    agg_kernel<<<NN, 128, 0, stream>>>(h2, csrc, cnorm, offs, dinv, convb2, 0,
                                       hbufs + (size_t)t * NN * HH);
    mask_kernel<<<(KK * HH + 255) / 256, 256, 0, stream>>>(
        node_t + (size_t)t * KK, hbufs + (size_t)t * NN * HH, KK);
  }

  // out[0] = mixer(zeros): identical for all nodes -> 1 row + broadcast
  mixer_kernel<<<1, 256, 0, stream>>>(hbufs, 0, tn_g, tn_b, tok_w1, tok_b1, tok_w2,
                                      tok_b2, cn_g, cn_b, ch_w1, ch_b1, ch_w2, ch_b2,
                                      out, 0, 1);
  bcast_kernel<<<((NN * HH - 128) + 255) / 256, 256, 0, stream>>>(out, NN * HH);

  for (int t = 1; t < 8; ++t) {
    mixer_kernel<<<256, 256, 0, stream>>>(hbufs, t, tn_g, tn_b, tok_w1, tok_b1, tok_w2,
                                          tok_b2, cn_g, cn_b, ch_w1, ch_b1, ch_w2, ch_b2,
                                          out + (size_t)t * NN * HH, 0, NN);
  }
}

// Round 6
// 5711.069 us; speedup vs baseline: 2.0789x; 2.0789x over previous
//
#include <hip/hip_runtime.h>
#include <hip/hip_bf16.h>
#include <cstdint>
#include <cstddef>

#define NN 20000
#define HH 128
#define MM 16
#define KK 4000
#define EE 400000

typedef __attribute__((ext_vector_type(4))) float f32x4;
// may-alias access types for reinterpret-casted traffic
typedef __attribute__((ext_vector_type(4), may_alias)) float f4ma;
typedef __attribute__((ext_vector_type(2), may_alias)) float f2ma;
typedef unsigned __attribute__((may_alias)) u32ma;
typedef float __attribute__((may_alias)) f32ma;

// Wave-local LDS ordering fence (compiler pin + completion wait).
#define LDS_FENCE() do { \
    asm volatile("s_waitcnt lgkmcnt(0)" ::: "memory"); \
    __builtin_amdgcn_sched_barrier(0); \
  } while (0)

__device__ __forceinline__ float gelu_f(float x) {
  return 0.5f * x * (1.0f + erff(x * 0.70710678118654752440f));
}

__device__ __forceinline__ unsigned short f2bf(float f) {
  union { float f; unsigned u; } v; v.f = f;
  unsigned u = v.u;
  unsigned r = (u + 0x7FFFu + ((u >> 16) & 1u)) >> 16;  // RNE
  return (unsigned short)r;
}
__device__ __forceinline__ float bf2f(unsigned short s) {
  union { unsigned u; float f; } v; v.u = ((unsigned)s) << 16; return v.f;
}
__device__ __forceinline__ void unpack2(unsigned w, float& lo, float& hi) {
  lo = bf2f((unsigned short)(w & 0xFFFFu));
  hi = bf2f((unsigned short)(w >> 16));
}

// ---------------- GCN helper kernels (validated in round 1) ----------------

__global__ void zero2_kernel(int* __restrict__ a, int* __restrict__ b, int n) {
  int i = blockIdx.x * 256 + threadIdx.x;
  if (i < n) { a[i] = 0; b[i] = 0; }
}

__global__ void count_kernel(const int* __restrict__ dst, int* __restrict__ cnt, int n) {
  int e = blockIdx.x * 256 + threadIdx.x;
  if (e < n) atomicAdd(&cnt[dst[e]], 1);
}

__global__ void dinv_kernel(const int* __restrict__ cnt, float* __restrict__ dinv, int n) {
  int i = blockIdx.x * 256 + threadIdx.x;
  if (i < n) dinv[i] = rsqrtf((float)(cnt[i] + 1));
}

__global__ void scan_kernel(const int* __restrict__ cnt, int* __restrict__ offs, int n) {
  __shared__ int sh[1024];
  __shared__ int carry_s;
  int tid = threadIdx.x;
  if (tid == 0) carry_s = 0;
  __syncthreads();
  for (int base = 0; base < n; base += 1024) {
    int i = base + tid;
    int v = (i < n) ? cnt[i] : 0;
    sh[tid] = v;
    __syncthreads();
    for (int off = 1; off < 1024; off <<= 1) {
      int t = (tid >= off) ? sh[tid - off] : 0;
      __syncthreads();
      sh[tid] += t;
      __syncthreads();
    }
    int carry = carry_s;
    if (i < n) offs[i] = carry + sh[tid] - v;
    __syncthreads();
    if (tid == 1023) carry_s = carry + sh[1023];
    __syncthreads();
  }
  if (tid == 0) offs[n] = carry_s;
}

__global__ void fillcsr_kernel(const int* __restrict__ esrc, const int* __restrict__ edst,
                               const int* __restrict__ offs, int* __restrict__ cursor,
                               const float* __restrict__ dinv,
                               int* __restrict__ csrc, float* __restrict__ cnorm, int n) {
  int e = blockIdx.x * 256 + threadIdx.x;
  if (e < n) {
    int s = esrc[e], d = edst[e];
    int pos = offs[d] + atomicAdd(&cursor[d], 1);
    csrc[pos] = s;
    cnorm[pos] = dinv[s] * dinv[d];
  }
}

__global__ __launch_bounds__(128) void agg_kernel(const float* __restrict__ X,
    const int* __restrict__ csrc, const float* __restrict__ cnorm,
    const int* __restrict__ offs, const float* __restrict__ dinv,
    const float* __restrict__ bias, int relu, float* __restrict__ Y) {
  int i = blockIdx.x, c = threadIdx.x;
  float di = dinv[i];
  float acc = X[(size_t)i * HH + c] * di * di;
  int s = offs[i], e = offs[i + 1];
  for (int j = s; j < e; ++j) {
    acc += X[(size_t)csrc[j] * HH + c] * cnorm[j];
  }
  acc += bias[c];
  if (relu) acc = fmaxf(acc, 0.f);
  Y[(size_t)i * HH + c] = acc;
}

__global__ __launch_bounds__(128) void gemm128_kernel(const float* __restrict__ X,
    const float* __restrict__ W, float* __restrict__ Y, int nrows) {
  __shared__ float Ws[128 * 129];
  __shared__ float Xs[8 * 128];
  int tid = threadIdx.x;
  for (int idx = tid; idx < 16384; idx += 128) {
    int o = idx >> 7, k = idx & 127;
    Ws[o * 129 + k] = W[idx];
  }
  __syncthreads();
  for (int row0 = blockIdx.x * 8; row0 < nrows; row0 += gridDim.x * 8) {
    int nr = min(8, nrows - row0);
    for (int idx = tid; idx < nr * 128; idx += 128) Xs[idx] = X[(size_t)row0 * 128 + idx];
    __syncthreads();
    float acc[8] = {0, 0, 0, 0, 0, 0, 0, 0};
    for (int k = 0; k < 128; ++k) {
      float w = Ws[tid * 129 + k];
#pragma unroll
      for (int r = 0; r < 8; ++r) acc[r] += w * Xs[r * 128 + k];
    }
    for (int r = 0; r < nr; ++r) Y[(size_t)(row0 + r) * 128 + tid] = acc[r];
    __syncthreads();
  }
}

__global__ void mask_kernel(const int* __restrict__ nodes, float* __restrict__ H, int kn) {
  int idx = blockIdx.x * 256 + threadIdx.x;
  if (idx < kn * HH) {
    int j = idx >> 7, c = idx & 127;
    H[(size_t)nodes[j] * HH + c] = 0.f;
  }
}

__global__ void bcast_kernel(float* __restrict__ out, int total) {
  int idx = blockIdx.x * 256 + threadIdx.x + 128;
  if (idx < total) out[idx] = out[idx & 127];
}

// ---------------- mixer v6: wave-per-node, f32-VALU channel-MLP ----------------
// Phases 1-4 identical to v5 (f32 tile, fences). Channel matmuls column-wise on
// the vector ALU: lane (q,h) owns output cols cb=q*32+2h, cb+1.
//   z rows read as uniform-address ds_read_b128 broadcasts (conflict-free);
//   W1/W2 staged TRANSPOSED bf16 [k][o] (u32 read spans 64 words -> 2-way, free);
//   hidden kept in registers, re-stored to the same tile between matmuls;
//   column sums are lane-local (no fout buffer, no MFMA).
// Only quantization left: W bf16 (~1e-3 at output).

__global__ __launch_bounds__(512, 2) void mixer6_kernel(
    const float* __restrict__ hbufs,  // [7][NN][HH]
    const float* __restrict__ tn_g, const float* __restrict__ tn_b,
    const float* __restrict__ tok_w1, const float* __restrict__ tok_b1,
    const float* __restrict__ tok_w2, const float* __restrict__ tok_b2,
    const float* __restrict__ cn_g, const float* __restrict__ cn_b,
    const float* __restrict__ ch_w1, const float* __restrict__ ch_b1,
    const float* __restrict__ ch_w2, const float* __restrict__ ch_b2,
    float* __restrict__ out, int total_items) {
  __shared__ __align__(16) unsigned short Wt1[128 * 128];  // 32 KB, [k][o] bf16
  __shared__ __align__(16) unsigned short Wt2[128 * 128];  // 32 KB
  __shared__ __align__(16) float zf[8][16 * 132];          // 67.6 KB per-wave tiles
  __shared__ float tg[128], tbv[128], cg[128], cbv[128], cb1v[128], cb2v[128];
  __shared__ float tw1s[256], tw2s[256], tb1s[16], tb2s[16];

  const int tid = threadIdx.x;

  // Stage W transposed: Wt[k*128+o] = bf16(W[o][k])
  for (int idx = tid; idx < 16384; idx += 512) {
    int o = idx >> 7, k = idx & 127;
    Wt1[k * 128 + o] = f2bf(ch_w1[idx]);
    Wt2[k * 128 + o] = f2bf(ch_w2[idx]);
  }
  if (tid < 128) {
    tg[tid] = tn_g[tid]; tbv[tid] = tn_b[tid];
    cg[tid] = cn_g[tid]; cbv[tid] = cn_b[tid];
    cb1v[tid] = ch_b1[tid]; cb2v[tid] = ch_b2[tid];
  }
  if (tid < 256) { tw1s[tid] = tok_w1[tid]; tw2s[tid] = tok_w2[tid]; }
  if (tid < 16) { tb1s[tid] = tok_b1[tid]; tb2s[tid] = tok_b2[tid]; }
  __syncthreads();  // only block barrier

  const int wid = tid >> 6;
  const int lane = tid & 63;
  const int q = lane >> 4;   // channel quarter
  const int h = lane & 15;   // token row
  f32ma* zw = (f32ma*)zf[wid];   // f32 view, pitch 132
  const int cb = q * 32 + 2 * h; // lane-private output column pair

  const int gwave = blockIdx.x * 8 + wid;
  const int wstride = gridDim.x * 8;

  for (int item = gwave; item < total_items; item += wstride) {
    int t, node;
    if (item < 7 * NN) { t = item / NN + 1; node = item % NN; }
    else { t = 0; node = 0; }

    // ---- 1. load window token h, channels q*32..+31 (f32 regs) ----
    float xr[32];
    {
      int src_t = h - (MM - t);
      if (src_t >= 0) {
        const float* hp = hbufs + ((size_t)src_t * NN + node) * HH + q * 32;
#pragma unroll
        for (int j = 0; j < 8; ++j) {
          f4ma v = *(const f4ma*)(hp + 4 * j);
          xr[4 * j] = v.x; xr[4 * j + 1] = v.y; xr[4 * j + 2] = v.z; xr[4 * j + 3] = v.w;
        }
      } else {
#pragma unroll
        for (int j = 0; j < 32; ++j) xr[j] = 0.f;
      }
    }

    // ---- 2. LN1 -> z1 f32 (row h, quarter q) ----
    {
      float s = 0.f, ss = 0.f;
#pragma unroll
      for (int j = 0; j < 32; ++j) { s += xr[j]; ss += xr[j] * xr[j]; }
      s += __shfl_xor(s, 16); ss += __shfl_xor(ss, 16);
      s += __shfl_xor(s, 32); ss += __shfl_xor(ss, 32);
      float mu = s * (1.f / 128.f);
      float var = fmaxf(ss * (1.f / 128.f) - mu * mu, 0.f);
      float rs = rsqrtf(var + 1e-5f);
#pragma unroll
      for (int m = 0; m < 8; ++m) {
        f4ma w;
        int c = q * 32 + 4 * m;
        w.x = (xr[4 * m]     - mu) * rs * tg[c]     + tbv[c];
        w.y = (xr[4 * m + 1] - mu) * rs * tg[c + 1] + tbv[c + 1];
        w.z = (xr[4 * m + 2] - mu) * rs * tg[c + 2] + tbv[c + 2];
        w.w = (xr[4 * m + 3] - mu) * rs * tg[c + 3] + tbv[c + 3];
        *(f4ma*)&zw[h * 132 + c] = w;
      }
    }
    LDS_FENCE();   // z1 visible to all lanes

    // ---- 3. token-MLP f32 on lane-private columns (cb, cb+1) ----
    {
      float z0[16], z1v[16];
#pragma unroll
      for (int r = 0; r < 16; ++r) {
        f2ma v = *(const f2ma*)&zw[r * 132 + cb];
        z0[r] = v.x; z1v[r] = v.y;
      }
      float a0[16], a1[16];
#pragma unroll
      for (int hd = 0; hd < 16; ++hd) { a0[hd] = tb1s[hd]; a1[hd] = tb1s[hd]; }
#pragma unroll
      for (int r = 0; r < 16; ++r) {
#pragma unroll
        for (int hd = 0; hd < 16; ++hd) {
          float w = tw1s[hd * 16 + r];
          a0[hd] += w * z0[r]; a1[hd] += w * z1v[r];
        }
      }
#pragma unroll
      for (int hd = 0; hd < 16; ++hd) { a0[hd] = gelu_f(a0[hd]); a1[hd] = gelu_f(a1[hd]); }
#pragma unroll
      for (int r = 0; r < 16; ++r) {
        float o0 = tb2s[r], o1 = tb2s[r];
#pragma unroll
        for (int hd = 0; hd < 16; ++hd) {
          float w = tw2s[r * 16 + hd];
          o0 += w * a0[hd]; o1 += w * a1[hd];
        }
        f2ma v; v.x = o0; v.y = o1;
        *(f2ma*)&zw[r * 132 + cb] = v;   // tok_out (private columns)
      }
    }
    LDS_FENCE();   // tok_out visible

    // ---- 4. x += tok_out; token-sum mx; LN2 -> z2 f32 ----
    float mx[32];
    {
#pragma unroll
      for (int j = 0; j < 8; ++j) {
        f4ma v = *(const f4ma*)&zw[h * 132 + q * 32 + 4 * j];
        xr[4 * j] += v.x; xr[4 * j + 1] += v.y; xr[4 * j + 2] += v.z; xr[4 * j + 3] += v.w;
      }
#pragma unroll
      for (int j = 0; j < 32; ++j) mx[j] = xr[j];
#pragma unroll
      for (int d = 1; d < 16; d <<= 1) {
#pragma unroll
        for (int j = 0; j < 32; ++j) mx[j] += __shfl_xor(mx[j], d);
      }
      float s = 0.f, ss = 0.f;
#pragma unroll
      for (int j = 0; j < 32; ++j) { s += xr[j]; ss += xr[j] * xr[j]; }
      s += __shfl_xor(s, 16); ss += __shfl_xor(ss, 16);
      s += __shfl_xor(s, 32); ss += __shfl_xor(ss, 32);
      float mu = s * (1.f / 128.f);
      float var = fmaxf(ss * (1.f / 128.f) - mu * mu, 0.f);
      float rs = rsqrtf(var + 1e-5f);
#pragma unroll
      for (int m = 0; m < 8; ++m) {
        f4ma w;
        int c = q * 32 + 4 * m;
        w.x = (xr[4 * m]     - mu) * rs * cg[c]     + cbv[c];
        w.y = (xr[4 * m + 1] - mu) * rs * cg[c + 1] + cbv[c + 1];
        w.z = (xr[4 * m + 2] - mu) * rs * cg[c + 2] + cbv[c + 2];
        w.w = (xr[4 * m + 3] - mu) * rs * cg[c + 3] + cbv[c + 3];
        *(f4ma*)&zw[h * 132 + c] = w;
      }
    }
    LDS_FENCE();   // z2 visible

    // ---- 5. channel matmul1 (f32 VALU): hidden = gelu(z2 @ W1^T + b1) ----
    float h0[16], h1[16];
    {
      float acc0[16], acc1[16];
      float b0 = cb1v[cb], b1 = cb1v[cb + 1];
#pragma unroll
      for (int r = 0; r < 16; ++r) { acc0[r] = b0; acc1[r] = b1; }
      for (int k = 0; k < 128; k += 4) {
        float w0[4], w1[4];
#pragma unroll
        for (int kk = 0; kk < 4; ++kk) {
          unsigned w = *(const u32ma*)&Wt1[(k + kk) * 128 + cb];
          unpack2(w, w0[kk], w1[kk]);
        }
#pragma unroll
        for (int r = 0; r < 16; ++r) {
          f4ma z4 = *(const f4ma*)&zw[r * 132 + k];   // uniform addr -> broadcast
          acc0[r] += z4.x * w0[0] + z4.y * w0[1] + z4.z * w0[2] + z4.w * w0[3];
          acc1[r] += z4.x * w1[0] + z4.y * w1[1] + z4.z * w1[2] + z4.w * w1[3];
        }
      }
#pragma unroll
      for (int r = 0; r < 16; ++r) { h0[r] = gelu_f(acc0[r]); h1[r] = gelu_f(acc1[r]); }
    }
    LDS_FENCE();   // all z2 reads done before overwrite (order pin)

    // store hidden to private columns
#pragma unroll
    for (int r = 0; r < 16; ++r) {
      f2ma v; v.x = h0[r]; v.y = h1[r];
      *(f2ma*)&zw[r * 132 + cb] = v;
    }
    LDS_FENCE();   // hidden visible

    // ---- 6. channel matmul2 (f32 VALU) + lane-local column sums ----
    float cs0, cs1;
    {
      float acc0[16], acc1[16];
      float b0 = cb2v[cb], b1 = cb2v[cb + 1];
#pragma unroll
      for (int r = 0; r < 16; ++r) { acc0[r] = b0; acc1[r] = b1; }
      for (int k = 0; k < 128; k += 4) {
        float w0[4], w1[4];
#pragma unroll
        for (int kk = 0; kk < 4; ++kk) {
          unsigned w = *(const u32ma*)&Wt2[(k + kk) * 128 + cb];
          unpack2(w, w0[kk], w1[kk]);
        }
#pragma unroll
        for (int r = 0; r < 16; ++r) {
          f4ma z4 = *(const f4ma*)&zw[r * 132 + k];
          acc0[r] += z4.x * w0[0] + z4.y * w0[1] + z4.z * w0[2] + z4.w * w0[3];
          acc1[r] += z4.x * w1[0] + z4.y * w1[1] + z4.z * w1[2] + z4.w * w1[3];
        }
      }
      cs0 = 0.f; cs1 = 0.f;
#pragma unroll
      for (int r = 0; r < 16; ++r) { cs0 += acc0[r]; cs1 += acc1[r]; }
    }

    // ---- 7. write output: (token-sum x + token-sum ch_out) / 16 ----
    {
      f2ma o;
      o.x = (mx[2 * h]     + cs0) * (1.f / 16.f);
      o.y = (mx[2 * h + 1] + cs1) * (1.f / 16.f);
      *(f2ma*)&out[((size_t)t * NN + node) * HH + cb] = o;
    }
    __builtin_amdgcn_sched_barrier(0);
  }
}

// ---------------- launch ----------------

extern "C" void kernel_launch(void* const* d_in, const int* in_sizes, int n_in,
                              void* d_out, int out_size, void* d_ws, size_t ws_size,
                              hipStream_t stream) {
  const int* node_t   = (const int*)d_in[0];
  const int* edges    = (const int*)d_in[1];
  const float* emb    = (const float*)d_in[3];
  const float* convW1 = (const float*)d_in[4];
  const float* convb1 = (const float*)d_in[5];
  const float* convW2 = (const float*)d_in[6];
  const float* convb2 = (const float*)d_in[7];
  const float* tn_g   = (const float*)d_in[8];
  const float* tn_b   = (const float*)d_in[9];
  const float* tok_w1 = (const float*)d_in[10];
  const float* tok_b1 = (const float*)d_in[11];
  const float* tok_w2 = (const float*)d_in[12];
  const float* tok_b2 = (const float*)d_in[13];
  const float* cn_g   = (const float*)d_in[14];
  const float* cn_b   = (const float*)d_in[15];
  const float* ch_w1  = (const float*)d_in[16];
  const float* ch_b1  = (const float*)d_in[17];
  const float* ch_w2  = (const float*)d_in[18];
  const float* ch_b2  = (const float*)d_in[19];
  float* out = (float*)d_out;

  char* ws = (char*)d_ws;
  size_t off = 0;
  auto alloc = [&](size_t bytes) -> void* {
    void* p = ws + off;
    off += (bytes + 511) & ~(size_t)511;
    return p;
  };
  float* xw1   = (float*)alloc((size_t)NN * HH * 4);
  float* hbufs = (float*)alloc((size_t)7 * NN * HH * 4);
  float* h     = (float*)alloc((size_t)NN * HH * 4);
  float* h2    = (float*)alloc((size_t)NN * HH * 4);
  float* dinv  = (float*)alloc((size_t)NN * 4);
  int*   cnt   = (int*)alloc((size_t)NN * 4);
  int*   cursor= (int*)alloc((size_t)NN * 4);
  int*   offs  = (int*)alloc((size_t)(NN + 1) * 4);
  int*   csrc  = (int*)alloc((size_t)EE * 4);
  float* cnorm = (float*)alloc((size_t)EE * 4);

  gemm128_kernel<<<512, 128, 0, stream>>>(emb, convW1, xw1, NN);

  for (int t = 0; t < 7; ++t) {
    const int* es = edges + (size_t)t * 2 * EE;
    const int* ed = es + EE;
    zero2_kernel<<<(NN + 255) / 256, 256, 0, stream>>>(cnt, cursor, NN);
    count_kernel<<<(EE + 255) / 256, 256, 0, stream>>>(ed, cnt, EE);
    dinv_kernel<<<(NN + 255) / 256, 256, 0, stream>>>(cnt, dinv, NN);
    scan_kernel<<<1, 1024, 0, stream>>>(cnt, offs, NN);
    fillcsr_kernel<<<(EE + 255) / 256, 256, 0, stream>>>(es, ed, offs, cursor, dinv,
                                                         csrc, cnorm, EE);
    agg_kernel<<<NN, 128, 0, stream>>>(xw1, csrc, cnorm, offs, dinv, convb1, 1, h);
    gemm128_kernel<<<512, 128, 0, stream>>>(h, convW2, h2, NN);
    agg_kernel<<<NN, 128, 0, stream>>>(h2, csrc, cnorm, offs, dinv, convb2, 0,
                                       hbufs + (size_t)t * NN * HH);
    mask_kernel<<<(KK * HH + 255) / 256, 256, 0, stream>>>(
        node_t + (size_t)t * KK, hbufs + (size_t)t * NN * HH, KK);
  }

  // One fused launch: items [0, 7*NN) = (t=1..7, node); item 7*NN = (t=0, node 0)
  mixer6_kernel<<<256, 512, 0, stream>>>(hbufs, tn_g, tn_b, tok_w1, tok_b1, tok_w2,
                                         tok_b2, cn_g, cn_b, ch_w1, ch_b1, ch_w2, ch_b2,
                                         out, 7 * NN + 1);
  bcast_kernel<<<((NN * HH - 128) + 255) / 256, 256, 0, stream>>>(out, NN * HH);
}